// Round 7
// baseline (1074.861 us; speedup 1.0000x reference)
//
#include <hip/hip_runtime.h>
#include <math.h>

// Problem constants (match reference)
#define NU_ 500000
#define NI_ 200000
#define NN_ 700000            // NU + NI
#define D_  64
#define E_  2000000
#define B_  131072
#define CAP_ 40               // fixed bucket capacity (max deg ~28, >10 sigma)

typedef _Float16 half4 __attribute__((ext_vector_type(4)));  // 8 B
typedef _Float16 half8 __attribute__((ext_vector_type(8)));  // 16 B

// ---------------------------------------------------------------------------
// One-pass CSR build into fixed-stride buckets: the atomic return IS the
// slot, and bucket base v*CAP_ needs no prefix scan. Slot order within a
// bucket is nondeterministic — only permutes fp summation order.
__global__ __launch_bounds__(256) void deg_fill_kernel(const int* __restrict__ eu,
                                                       const int* __restrict__ ei,
                                                       int* __restrict__ cnt,
                                                       int* __restrict__ adjb) {
    int e = blockIdx.x * 256 + threadIdx.x;
    if (e >= E_) return;
    int su = eu[e];
    int sv = ei[e] + NU_;
    int p = atomicAdd(&cnt[su], 1);
    adjb[(size_t)su * CAP_ + p] = sv;
    int q = atomicAdd(&cnt[sv], 1);
    adjb[(size_t)sv * CAP_ + q] = su;
}

__global__ __launch_bounds__(256) void inv_kernel(const int* __restrict__ cnt,
                                                  float* __restrict__ inv) {
    int v = blockIdx.x * 256 + threadIdx.x;
    if (v >= NN_) return;
    int d = cnt[v];
    inv[v] = (d > 0) ? (1.0f / sqrtf((float)d)) : 0.0f;
}

// ---------------------------------------------------------------------------
// Convert the concatenated [ue; ie] f32 embeddings to fp16 rows (128 B/row).
__global__ __launch_bounds__(256) void conv_kernel(const float* __restrict__ ue,
                                                   const float* __restrict__ ie,
                                                   half4* __restrict__ xh) {
    int t = blockIdx.x * 256 + threadIdx.x;
    int b = t >> 4;
    int q = t & 15;
    const float4* src = (b < NU_)
        ? ((const float4*)(ue + (size_t)b * D_) + q)
        : ((const float4*)(ie + (size_t)(b - NU_) * D_) + q);
    float4 a = *src;
    half4 h;
    h[0] = (_Float16)a.x; h[1] = (_Float16)a.y;
    h[2] = (_Float16)a.z; h[3] = (_Float16)a.w;
    xh[(size_t)b * 16 + q] = h;
}

// ---------------------------------------------------------------------------
// fp16 pull from fixed buckets: lane = g*8+q; g = neighbor slot (8),
// q = feature octet (16 B). Up to 5 8-row steps (CAP_=40).
// out[v][:] = fp16( inv[v] * sum_n inv[n] * x[n][:] ), accumulation in f32.
__global__ __launch_bounds__(256) void pull_kernel(const half8* __restrict__ xh,
                                                   const float* __restrict__ inv,
                                                   const int* __restrict__ cnt,
                                                   const int* __restrict__ adjb,
                                                   half8* __restrict__ out) {
    int t = blockIdx.x * 256 + threadIdx.x;
    int v = t >> 6;
    int lane = t & 63;
    int g = lane >> 3;        // neighbor slot (0..7)
    int q = lane & 7;         // feature octet (features 8q..8q+7)
    int deg = cnt[v];
    const int* bucket = adjb + (size_t)v * CAP_;
    float acc[8] = {0.f, 0.f, 0.f, 0.f, 0.f, 0.f, 0.f, 0.f};
    for (int s = 0; s < deg; s += 8) {
        int idx = s + g;                      // <= 39 always in-bucket
        bool valid = idx < deg;
        int n = bucket[idx];                  // garbage if !valid
        n = valid ? n : 0;                    // clamp before use
        float w = valid ? inv[n] : 0.0f;      // inv is 2.8MB, L2-resident
        half8 a = xh[(size_t)n * 8 + q];
#pragma unroll
        for (int k = 0; k < 8; ++k)
            acc[k] += w * (float)a[k];
    }
    // combine the 8 neighbor slots (g occupies lane bits 3..5)
#pragma unroll
    for (int k = 0; k < 8; ++k) {
        acc[k] += __shfl_xor(acc[k], 8);
        acc[k] += __shfl_xor(acc[k], 16);
        acc[k] += __shfl_xor(acc[k], 32);
    }
    if (g == 0) {
        float iv = inv[v];
        half8 o;
#pragma unroll
        for (int k = 0; k < 8; ++k) o[k] = (_Float16)(iv * acc[k]);
        out[(size_t)v * 8 + q] = o;
    }
}

// ---------------------------------------------------------------------------
// Final layer fused: pull only the gathered rows, accumulate into f32 Z.
__global__ __launch_bounds__(256) void pullz_kernel(const half8* __restrict__ xh,
                                                    const float* __restrict__ inv,
                                                    const int* __restrict__ cnt,
                                                    const int* __restrict__ adjb,
                                                    const int* __restrict__ users,
                                                    const int* __restrict__ items,
                                                    float* __restrict__ Zu,
                                                    float* __restrict__ Zi) {
    int t = blockIdx.x * 256 + threadIdx.x;
    int b = t >> 6;
    int lane = t & 63;
    int g = lane >> 3;
    int q = lane & 7;
    int node;
    float* Z;
    if (b < B_) { node = users[b];            Z = Zu + (size_t)b * D_; }
    else        { node = items[b - B_] + NU_; Z = Zi + (size_t)(b - B_) * D_; }
    int deg = cnt[node];
    const int* bucket = adjb + (size_t)node * CAP_;
    float acc[8] = {0.f, 0.f, 0.f, 0.f, 0.f, 0.f, 0.f, 0.f};
    for (int s = 0; s < deg; s += 8) {
        int idx = s + g;
        bool valid = idx < deg;
        int n = bucket[idx];
        n = valid ? n : 0;
        float w = valid ? inv[n] : 0.0f;
        half8 a = xh[(size_t)n * 8 + q];
#pragma unroll
        for (int k = 0; k < 8; ++k)
            acc[k] += w * (float)a[k];
    }
#pragma unroll
    for (int k = 0; k < 8; ++k) {
        acc[k] += __shfl_xor(acc[k], 8);
        acc[k] += __shfl_xor(acc[k], 16);
        acc[k] += __shfl_xor(acc[k], 32);
    }
    if (g == 0) {
        float iv = inv[node];
        float4* zp = (float4*)Z + 2 * q;          // features 8q..8q+7
        float4 z0 = zp[0], z1 = zp[1];
        z0.x += iv * acc[0]; z0.y += iv * acc[1];
        z0.z += iv * acc[2]; z0.w += iv * acc[3];
        z1.x += iv * acc[4]; z1.y += iv * acc[5];
        z1.z += iv * acc[6]; z1.w += iv * acc[7];
        zp[0] = z0; zp[1] = z1;
    }
}

// ---------------------------------------------------------------------------
// Fused Z init + layer-1 accumulate: Z = emb(f32, exact) + layer1(fp16).
__global__ __launch_bounds__(256) void zinit_acc_kernel(const float* __restrict__ ue,
                                                        const float* __restrict__ ie,
                                                        const half4* __restrict__ xh,
                                                        const int* __restrict__ users,
                                                        const int* __restrict__ items,
                                                        float* __restrict__ Zu,
                                                        float* __restrict__ Zi) {
    int t = blockIdx.x * 256 + threadIdx.x;
    int b = t >> 4;
    int q = t & 15;
    size_t node;
    const float4* ep;
    float4* zp;
    if (b < B_) {
        node = (size_t)users[b];
        ep = (const float4*)(ue + node * D_) + q;
        zp = (float4*)(Zu + (size_t)b * D_) + q;
    } else {
        int bb = b - B_;
        node = (size_t)items[bb] + NU_;
        ep = (const float4*)(ie + (size_t)items[bb] * D_) + q;
        zp = (float4*)(Zi + (size_t)bb * D_) + q;
    }
    half4 a = xh[node * 16 + q];
    float4 z = *ep;
    z.x += (float)a[0]; z.y += (float)a[1];
    z.z += (float)a[2]; z.w += (float)a[3];
    *zp = z;
}

// Accumulate a fp16 layer at the gathered rows into f32 Z.
__global__ __launch_bounds__(256) void zacc_kernel(const half4* __restrict__ xh,
                                                   const int* __restrict__ users,
                                                   const int* __restrict__ items,
                                                   float* __restrict__ Zu,
                                                   float* __restrict__ Zi) {
    int t = blockIdx.x * 256 + threadIdx.x;
    int b = t >> 4;
    int q = t & 15;
    float4* zp;
    size_t node;
    if (b < B_) {
        zp = (float4*)(Zu + (size_t)b * D_) + q;
        node = (size_t)users[b];
    } else {
        int bb = b - B_;
        zp = (float4*)(Zi + (size_t)bb * D_) + q;
        node = (size_t)items[bb] + NU_;
    }
    half4 a = xh[node * 16 + q];
    float4 z = *zp;
    z.x += (float)a[0]; z.y += (float)a[1];
    z.z += (float)a[2]; z.w += (float)a[3];
    *zp = z;
}

// ---------------------------------------------------------------------------
// One wave per pair b. Lane l: f = l>>4, d = l&15.
__global__ __launch_bounds__(256) void score_kernel(const float* __restrict__ Zu,
                                                    const float* __restrict__ Zi,
                                                    const float* __restrict__ fw,
                                                    float* __restrict__ out) {
    int t = blockIdx.x * 256 + threadIdx.x;
    int b = t >> 6;
    int l = t & 63;
    int f = l >> 4;
    int dd = l & 15;
    float pu = Zu[(size_t)b * D_ + l];
    float s = 0.0f;
#pragma unroll
    for (int g = 0; g < 4; ++g) {
        float pi = Zi[(size_t)b * D_ + g * 16 + dd];
        float p = pu * pi;
        p += __shfl_xor(p, 1);
        p += __shfl_xor(p, 2);
        p += __shfl_xor(p, 4);
        p += __shfl_xor(p, 8);
        s += fw[f * 4 + g] * p;
    }
    s += __shfl_xor(s, 16);
    s += __shfl_xor(s, 32);
    if (l == 0) out[b] = s * 0.0625f;  // (1/4)*(1/4) layer-mean scaling
}

// ---------------------------------------------------------------------------
extern "C" void kernel_launch(void* const* d_in, const int* in_sizes, int n_in,
                              void* d_out, int out_size, void* d_ws, size_t ws_size,
                              hipStream_t stream) {
    const float* ue    = (const float*)d_in[0];  // [NU, 64]
    const float* ie    = (const float*)d_in[1];  // [NI, 64]
    const float* fw    = (const float*)d_in[2];  // [4, 4]
    const int*   eu    = (const int*)d_in[3];    // [E]
    const int*   eitem = (const int*)d_in[4];    // [E]
    const int*   users = (const int*)d_in[5];    // [B]
    const int*   items = (const int*)d_in[6];    // [B]
    float* scores = (float*)d_out;               // [B]

    const size_t xh_bytes = (size_t)NN_ * D_ * 2;             // 89.6 MB (fp16)
    const size_t zbytes   = (size_t)B_ * D_ * sizeof(float);  // 33.55 MB

    char* ws = (char*)d_ws;
    half8* X0h  = (half8*)ws;  ws += xh_bytes;   // layer-0; reused as layer-2 out
    half8* XAh  = (half8*)ws;  ws += xh_bytes;   // layer-1
    float* Zu   = (float*)ws;  ws += zbytes;
    float* Zi   = (float*)ws;  ws += zbytes;
    float* inv  = (float*)ws;  ws += (size_t)NN_ * 4;
    int*   cnt  = (int*)ws;    ws += (size_t)NN_ * 4;
    int*   adjb = (int*)ws;    ws += (size_t)NN_ * CAP_ * 4;  // 112 MB
    half8* XBh  = X0h;         // ping-pong: X0h dead after layer-1 pull

    // --- one-pass bucket CSR build -------------------------------------
    hipMemsetAsync(cnt, 0, (size_t)NN_ * 4, stream);
    deg_fill_kernel<<<(E_ + 255) / 256, 256, 0, stream>>>(eu, eitem, cnt, adjb);
    inv_kernel<<<(NN_ + 255) / 256, 256, 0, stream>>>(cnt, inv);

    // --- fp16 conversion of layer-0 X ----------------------------------
    conv_kernel<<<(NN_ * 16) / 256, 256, 0, stream>>>(ue, ie, (half4*)X0h);

    // --- 3 propagation layers (fp16 pull from buckets) -----------------
    pull_kernel<<<(NN_ * D_) / 256, 256, 0, stream>>>(X0h, inv, cnt, adjb, XAh);
    // Z = emb(f32) + layer1, fused
    zinit_acc_kernel<<<(2 * B_ * 16) / 256, 256, 0, stream>>>(
        ue, ie, (const half4*)XAh, users, items, Zu, Zi);
    pull_kernel<<<(NN_ * D_) / 256, 256, 0, stream>>>(XAh, inv, cnt, adjb, XBh);
    zacc_kernel<<<(2 * B_ * 16) / 256, 256, 0, stream>>>(
        (const half4*)XBh, users, items, Zu, Zi);
    // Layer 3: only the gathered rows are needed — fuse into Z.
    pullz_kernel<<<(2 * B_ * D_) / 256, 256, 0, stream>>>(
        XBh, inv, cnt, adjb, users, items, Zu, Zi);

    // --- scores --------------------------------------------------------
    score_kernel<<<(B_ * D_) / 256, 256, 0, stream>>>(Zu, Zi, fw, scores);
}

// Round 8
// 1013.848 us; speedup vs baseline: 1.0602x; 1.0602x over previous
//
#include <hip/hip_runtime.h>
#include <math.h>

// Problem constants (match reference)
#define NU_ 500000
#define NI_ 200000
#define NN_ 700000            // NU + NI
#define D_  64
#define E_  2000000
#define B_  131072
#define TWO_E 4000000

typedef _Float16 half4 __attribute__((ext_vector_type(4)));  // 8 B
typedef _Float16 half8 __attribute__((ext_vector_type(8)));  // 16 B

// ---------------------------------------------------------------------------
// Degree histogram + rank assignment, one endpoint per thread (2E threads).
// The atomic return IS the entry's rank within its endpoint's CSR row.
__global__ __launch_bounds__(256) void deg_rank_kernel(const int* __restrict__ eu,
                                                       const int* __restrict__ ei,
                                                       int* __restrict__ cnt,
                                                       int* __restrict__ rk) {
    int t = blockIdx.x * 256 + threadIdx.x;   // t < 2E
    int e = t >> 1;
    int side = t & 1;
    int node = side ? (ei[e] + NU_) : eu[e];
    rk[t] = atomicAdd(&cnt[node], 1);
}

__global__ __launch_bounds__(256) void inv_kernel(const int* __restrict__ cnt,
                                                  float* __restrict__ inv) {
    int v = blockIdx.x * 256 + threadIdx.x;
    if (v >= NN_) return;
    int d = cnt[v];
    inv[v] = (d > 0) ? (1.0f / sqrtf((float)d)) : 0.0f;
}

// ---------------------------------------------------------------------------
// Two-level exclusive scan (1024 elements per block, Hillis-Steele in LDS).
__global__ __launch_bounds__(1024) void scan_block(const int* __restrict__ in, int n,
                                                   int* __restrict__ out,
                                                   int* __restrict__ psum) {
    __shared__ int lds[1024];
    int g = blockIdx.x * 1024 + threadIdx.x;
    int v = (g < n) ? in[g] : 0;
    lds[threadIdx.x] = v;
    __syncthreads();
    for (int off = 1; off < 1024; off <<= 1) {
        int t = (threadIdx.x >= (unsigned)off) ? lds[threadIdx.x - off] : 0;
        __syncthreads();
        lds[threadIdx.x] += t;
        __syncthreads();
    }
    if (g < n) out[g] = lds[threadIdx.x] - v;     // exclusive
    if (threadIdx.x == 1023 && psum) psum[blockIdx.x] = lds[1023];
}

__global__ __launch_bounds__(256) void scan_add(int* __restrict__ rowptr,
                                                const int* __restrict__ poff) {
    int g = blockIdx.x * 256 + threadIdx.x;
    if (g < NN_) rowptr[g] += poff[g >> 10];
    if (g == 0) rowptr[NN_] = TWO_E;              // total is statically known
}

// ---------------------------------------------------------------------------
// CSR fill via atomicExch: atomic RMWs execute at the cache-side coherence
// point, so the 16 MB adj array's lines merge all entries before ONE
// writeback — unlike plain scattered stores (write-through, 64B per 4B store,
// measured 247 MB in R7). Slot positions are deterministic except for the
// atomic rank order (permutes fp summation only).
__global__ __launch_bounds__(256) void fill2_kernel(const int* __restrict__ eu,
                                                    const int* __restrict__ ei,
                                                    const int* __restrict__ rk,
                                                    const int* __restrict__ rowptr,
                                                    int* __restrict__ adj) {
    int t = blockIdx.x * 256 + threadIdx.x;   // t < 2E
    int e = t >> 1;
    int side = t & 1;
    int su = eu[e];
    int sv = ei[e] + NU_;
    int node = side ? sv : su;
    int nbr  = side ? su : sv;
    atomicExch(&adj[rowptr[node] + rk[t]], nbr);
}

// ---------------------------------------------------------------------------
// Convert the concatenated [ue; ie] f32 embeddings to fp16 rows (128 B/row).
__global__ __launch_bounds__(256) void conv_kernel(const float* __restrict__ ue,
                                                   const float* __restrict__ ie,
                                                   half4* __restrict__ xh) {
    int t = blockIdx.x * 256 + threadIdx.x;
    int b = t >> 4;
    int q = t & 15;
    const float4* src = (b < NU_)
        ? ((const float4*)(ue + (size_t)b * D_) + q)
        : ((const float4*)(ie + (size_t)(b - NU_) * D_) + q);
    float4 a = *src;
    half4 h;
    h[0] = (_Float16)a.x; h[1] = (_Float16)a.y;
    h[2] = (_Float16)a.z; h[3] = (_Float16)a.w;
    xh[(size_t)b * 16 + q] = h;
}

// ---------------------------------------------------------------------------
// fp16 pull (compact CSR): lane = g*8+q; g = neighbor slot (8), q = feature
// octet (16 B). 8 rows in flight per wave per step.
// out[v][:] = fp16( inv[v] * sum_n inv[n] * x[n][:] ), accumulation in f32.
__global__ __launch_bounds__(256) void pull_kernel(const half8* __restrict__ xh,
                                                   const float* __restrict__ inv,
                                                   const int* __restrict__ rowptr,
                                                   const int* __restrict__ adj,
                                                   half8* __restrict__ out) {
    int t = blockIdx.x * 256 + threadIdx.x;
    int v = t >> 6;
    int lane = t & 63;
    int g = lane >> 3;        // neighbor slot (0..7)
    int q = lane & 7;         // feature octet (features 8q..8q+7)
    int beg = rowptr[v];
    int end = rowptr[v + 1];
    float acc[8] = {0.f, 0.f, 0.f, 0.f, 0.f, 0.f, 0.f, 0.f};
    for (int j = beg; j < end; j += 8) {
        int i = j + g;
        bool valid = i < end;
        int n = valid ? adj[i] : 0;           // guarded (last row touches 2E)
        float w = valid ? inv[n] : 0.0f;      // inv is 2.8MB, L2-resident
        half8 a = xh[(size_t)n * 8 + q];
#pragma unroll
        for (int k = 0; k < 8; ++k)
            acc[k] += w * (float)a[k];
    }
    // combine the 8 neighbor slots (g occupies lane bits 3..5)
#pragma unroll
    for (int k = 0; k < 8; ++k) {
        acc[k] += __shfl_xor(acc[k], 8);
        acc[k] += __shfl_xor(acc[k], 16);
        acc[k] += __shfl_xor(acc[k], 32);
    }
    if (g == 0) {
        float iv = inv[v];
        half8 o;
#pragma unroll
        for (int k = 0; k < 8; ++k) o[k] = (_Float16)(iv * acc[k]);
        out[(size_t)v * 8 + q] = o;
    }
}

// ---------------------------------------------------------------------------
// Final layer fused: pull only the gathered rows, accumulate into f32 Z.
__global__ __launch_bounds__(256) void pullz_kernel(const half8* __restrict__ xh,
                                                    const float* __restrict__ inv,
                                                    const int* __restrict__ rowptr,
                                                    const int* __restrict__ adj,
                                                    const int* __restrict__ users,
                                                    const int* __restrict__ items,
                                                    float* __restrict__ Zu,
                                                    float* __restrict__ Zi) {
    int t = blockIdx.x * 256 + threadIdx.x;
    int b = t >> 6;
    int lane = t & 63;
    int g = lane >> 3;
    int q = lane & 7;
    int node;
    float* Z;
    if (b < B_) { node = users[b];            Z = Zu + (size_t)b * D_; }
    else        { node = items[b - B_] + NU_; Z = Zi + (size_t)(b - B_) * D_; }
    int beg = rowptr[node];
    int end = rowptr[node + 1];
    float acc[8] = {0.f, 0.f, 0.f, 0.f, 0.f, 0.f, 0.f, 0.f};
    for (int j = beg; j < end; j += 8) {
        int i = j + g;
        bool valid = i < end;
        int n = valid ? adj[i] : 0;
        float w = valid ? inv[n] : 0.0f;
        half8 a = xh[(size_t)n * 8 + q];
#pragma unroll
        for (int k = 0; k < 8; ++k)
            acc[k] += w * (float)a[k];
    }
#pragma unroll
    for (int k = 0; k < 8; ++k) {
        acc[k] += __shfl_xor(acc[k], 8);
        acc[k] += __shfl_xor(acc[k], 16);
        acc[k] += __shfl_xor(acc[k], 32);
    }
    if (g == 0) {
        float iv = inv[node];
        float4* zp = (float4*)Z + 2 * q;          // features 8q..8q+7
        float4 z0 = zp[0], z1 = zp[1];
        z0.x += iv * acc[0]; z0.y += iv * acc[1];
        z0.z += iv * acc[2]; z0.w += iv * acc[3];
        z1.x += iv * acc[4]; z1.y += iv * acc[5];
        z1.z += iv * acc[6]; z1.w += iv * acc[7];
        zp[0] = z0; zp[1] = z1;
    }
}

// ---------------------------------------------------------------------------
// Fused Z init + layer-1 accumulate: Z = emb(f32, exact) + layer1(fp16).
__global__ __launch_bounds__(256) void zinit_acc_kernel(const float* __restrict__ ue,
                                                        const float* __restrict__ ie,
                                                        const half4* __restrict__ xh,
                                                        const int* __restrict__ users,
                                                        const int* __restrict__ items,
                                                        float* __restrict__ Zu,
                                                        float* __restrict__ Zi) {
    int t = blockIdx.x * 256 + threadIdx.x;
    int b = t >> 4;
    int q = t & 15;
    size_t node;
    const float4* ep;
    float4* zp;
    if (b < B_) {
        node = (size_t)users[b];
        ep = (const float4*)(ue + node * D_) + q;
        zp = (float4*)(Zu + (size_t)b * D_) + q;
    } else {
        int bb = b - B_;
        node = (size_t)items[bb] + NU_;
        ep = (const float4*)(ie + (size_t)items[bb] * D_) + q;
        zp = (float4*)(Zi + (size_t)bb * D_) + q;
    }
    half4 a = xh[node * 16 + q];
    float4 z = *ep;
    z.x += (float)a[0]; z.y += (float)a[1];
    z.z += (float)a[2]; z.w += (float)a[3];
    *zp = z;
}

// Accumulate a fp16 layer at the gathered rows into f32 Z.
__global__ __launch_bounds__(256) void zacc_kernel(const half4* __restrict__ xh,
                                                   const int* __restrict__ users,
                                                   const int* __restrict__ items,
                                                   float* __restrict__ Zu,
                                                   float* __restrict__ Zi) {
    int t = blockIdx.x * 256 + threadIdx.x;
    int b = t >> 4;
    int q = t & 15;
    float4* zp;
    size_t node;
    if (b < B_) {
        zp = (float4*)(Zu + (size_t)b * D_) + q;
        node = (size_t)users[b];
    } else {
        int bb = b - B_;
        zp = (float4*)(Zi + (size_t)bb * D_) + q;
        node = (size_t)items[bb] + NU_;
    }
    half4 a = xh[node * 16 + q];
    float4 z = *zp;
    z.x += (float)a[0]; z.y += (float)a[1];
    z.z += (float)a[2]; z.w += (float)a[3];
    *zp = z;
}

// ---------------------------------------------------------------------------
// One wave per pair b. Lane l: f = l>>4, d = l&15.
__global__ __launch_bounds__(256) void score_kernel(const float* __restrict__ Zu,
                                                    const float* __restrict__ Zi,
                                                    const float* __restrict__ fw,
                                                    float* __restrict__ out) {
    int t = blockIdx.x * 256 + threadIdx.x;
    int b = t >> 6;
    int l = t & 63;
    int f = l >> 4;
    int dd = l & 15;
    float pu = Zu[(size_t)b * D_ + l];
    float s = 0.0f;
#pragma unroll
    for (int g = 0; g < 4; ++g) {
        float pi = Zi[(size_t)b * D_ + g * 16 + dd];
        float p = pu * pi;
        p += __shfl_xor(p, 1);
        p += __shfl_xor(p, 2);
        p += __shfl_xor(p, 4);
        p += __shfl_xor(p, 8);
        s += fw[f * 4 + g] * p;
    }
    s += __shfl_xor(s, 16);
    s += __shfl_xor(s, 32);
    if (l == 0) out[b] = s * 0.0625f;  // (1/4)*(1/4) layer-mean scaling
}

// ---------------------------------------------------------------------------
extern "C" void kernel_launch(void* const* d_in, const int* in_sizes, int n_in,
                              void* d_out, int out_size, void* d_ws, size_t ws_size,
                              hipStream_t stream) {
    const float* ue    = (const float*)d_in[0];  // [NU, 64]
    const float* ie    = (const float*)d_in[1];  // [NI, 64]
    const float* fw    = (const float*)d_in[2];  // [4, 4]
    const int*   eu    = (const int*)d_in[3];    // [E]
    const int*   eitem = (const int*)d_in[4];    // [E]
    const int*   users = (const int*)d_in[5];    // [B]
    const int*   items = (const int*)d_in[6];    // [B]
    float* scores = (float*)d_out;               // [B]

    const size_t xh_bytes = (size_t)NN_ * D_ * 2;             // 89.6 MB (fp16)
    const size_t zbytes   = (size_t)B_ * D_ * sizeof(float);  // 33.55 MB
    const int NB_SCAN = (NN_ + 1023) / 1024;                  // 684

    char* ws = (char*)d_ws;
    half8* X0h   = (half8*)ws;  ws += xh_bytes;   // layer-0; reused as layer-2 out
    half8* XAh   = (half8*)ws;  ws += xh_bytes;   // layer-1
    float* Zu    = (float*)ws;  ws += zbytes;
    float* Zi    = (float*)ws;  ws += zbytes;
    float* inv   = (float*)ws;  ws += (size_t)NN_ * 4;
    int*   cnt   = (int*)ws;    ws += (size_t)NN_ * 4;
    int*   rowptr= (int*)ws;    ws += (size_t)(NN_ + 1) * 4;
    int*   adj   = (int*)ws;    ws += (size_t)TWO_E * 4;      // 16 MB compact
    int*   rk    = (int*)ws;    ws += (size_t)TWO_E * 4;      // 16 MB ranks
    int*   psum  = (int*)ws;    ws += (size_t)NB_SCAN * 4;
    int*   poff  = (int*)ws;    ws += (size_t)NB_SCAN * 4;
    half8* XBh   = X0h;         // ping-pong: X0h dead after layer-1 pull

    // --- CSR build: rank-from-degree + atomicExch fill -----------------
    hipMemsetAsync(cnt, 0, (size_t)NN_ * 4, stream);
    deg_rank_kernel<<<TWO_E / 256, 256, 0, stream>>>(eu, eitem, cnt, rk);
    inv_kernel<<<(NN_ + 255) / 256, 256, 0, stream>>>(cnt, inv);
    scan_block<<<NB_SCAN, 1024, 0, stream>>>(cnt, NN_, rowptr, psum);
    scan_block<<<1, 1024, 0, stream>>>(psum, NB_SCAN, poff, (int*)nullptr);
    scan_add<<<(NN_ + 255) / 256, 256, 0, stream>>>(rowptr, poff);
    fill2_kernel<<<TWO_E / 256, 256, 0, stream>>>(eu, eitem, rk, rowptr, adj);

    // --- fp16 conversion of layer-0 X ----------------------------------
    conv_kernel<<<(NN_ * 16) / 256, 256, 0, stream>>>(ue, ie, (half4*)X0h);

    // --- 3 propagation layers (fp16 pull) ------------------------------
    pull_kernel<<<(NN_ * D_) / 256, 256, 0, stream>>>(X0h, inv, rowptr, adj, XAh);
    // Z = emb(f32) + layer1, fused
    zinit_acc_kernel<<<(2 * B_ * 16) / 256, 256, 0, stream>>>(
        ue, ie, (const half4*)XAh, users, items, Zu, Zi);
    pull_kernel<<<(NN_ * D_) / 256, 256, 0, stream>>>(XAh, inv, rowptr, adj, XBh);
    zacc_kernel<<<(2 * B_ * 16) / 256, 256, 0, stream>>>(
        (const half4*)XBh, users, items, Zu, Zi);
    // Layer 3: only the gathered rows are needed — fuse into Z.
    pullz_kernel<<<(2 * B_ * D_) / 256, 256, 0, stream>>>(
        XBh, inv, rowptr, adj, users, items, Zu, Zi);

    // --- scores --------------------------------------------------------
    score_kernel<<<(B_ * D_) / 256, 256, 0, stream>>>(Zu, Zi, fw, scores);
}

// Round 9
// 1003.023 us; speedup vs baseline: 1.0716x; 1.0108x over previous
//
#include <hip/hip_runtime.h>
#include <math.h>

// Problem constants (match reference)
#define NU_ 500000
#define NI_ 200000
#define NN_ 700000            // NU + NI
#define D_  64
#define E_  2000000
#define B_  131072
#define TWO_E 4000000

typedef _Float16 half4 __attribute__((ext_vector_type(4)));  // 8 B
typedef _Float16 half8 __attribute__((ext_vector_type(8)));  // 16 B

// ---------------------------------------------------------------------------
// Degree histogram + rank assignment, one endpoint per thread (2E threads).
__global__ __launch_bounds__(256) void deg_rank_kernel(const int* __restrict__ eu,
                                                       const int* __restrict__ ei,
                                                       int* __restrict__ cnt,
                                                       int* __restrict__ rk) {
    int t = blockIdx.x * 256 + threadIdx.x;   // t < 2E
    int e = t >> 1;
    int side = t & 1;
    int node = side ? (ei[e] + NU_) : eu[e];
    rk[t] = atomicAdd(&cnt[node], 1);
}

__global__ __launch_bounds__(256) void inv_kernel(const int* __restrict__ cnt,
                                                  float* __restrict__ inv) {
    int v = blockIdx.x * 256 + threadIdx.x;
    if (v >= NN_) return;
    int d = cnt[v];
    inv[v] = (d > 0) ? (1.0f / sqrtf((float)d)) : 0.0f;
}

// ---------------------------------------------------------------------------
// Two-level exclusive scan (1024 elements per block, Hillis-Steele in LDS).
__global__ __launch_bounds__(1024) void scan_block(const int* __restrict__ in, int n,
                                                   int* __restrict__ out,
                                                   int* __restrict__ psum) {
    __shared__ int lds[1024];
    int g = blockIdx.x * 1024 + threadIdx.x;
    int v = (g < n) ? in[g] : 0;
    lds[threadIdx.x] = v;
    __syncthreads();
    for (int off = 1; off < 1024; off <<= 1) {
        int t = (threadIdx.x >= (unsigned)off) ? lds[threadIdx.x - off] : 0;
        __syncthreads();
        lds[threadIdx.x] += t;
        __syncthreads();
    }
    if (g < n) out[g] = lds[threadIdx.x] - v;     // exclusive
    if (threadIdx.x == 1023 && psum) psum[blockIdx.x] = lds[1023];
}

__global__ __launch_bounds__(256) void scan_add(int* __restrict__ rowptr,
                                                const int* __restrict__ poff) {
    int g = blockIdx.x * 256 + threadIdx.x;
    if (g < NN_) rowptr[g] += poff[g >> 10];
    if (g == 0) rowptr[NN_] = TWO_E;              // total is statically known
}

// ---------------------------------------------------------------------------
// CSR fill via atomicExch: RMW merges cache-side (R8 evidence: plain scattered
// stores emitted 247 MB write-through; atomicExch collapsed it).
__global__ __launch_bounds__(256) void fill2_kernel(const int* __restrict__ eu,
                                                    const int* __restrict__ ei,
                                                    const int* __restrict__ rk,
                                                    const int* __restrict__ rowptr,
                                                    int* __restrict__ adj) {
    int t = blockIdx.x * 256 + threadIdx.x;   // t < 2E
    int e = t >> 1;
    int side = t & 1;
    int su = eu[e];
    int sv = ei[e] + NU_;
    int node = side ? sv : su;
    int nbr  = side ? su : sv;
    atomicExch(&adj[rowptr[node] + rk[t]], nbr);
}

// ---------------------------------------------------------------------------
// Convert the concatenated [ue; ie] f32 embeddings to fp16 rows (128 B/row).
__global__ __launch_bounds__(256) void conv_kernel(const float* __restrict__ ue,
                                                   const float* __restrict__ ie,
                                                   half4* __restrict__ xh) {
    int t = blockIdx.x * 256 + threadIdx.x;
    int b = t >> 4;
    int q = t & 15;
    const float4* src = (b < NU_)
        ? ((const float4*)(ue + (size_t)b * D_) + q)
        : ((const float4*)(ie + (size_t)(b - NU_) * D_) + q);
    float4 a = *src;
    half4 h;
    h[0] = (_Float16)a.x; h[1] = (_Float16)a.y;
    h[2] = (_Float16)a.z; h[3] = (_Float16)a.w;
    xh[(size_t)b * 16 + q] = h;
}

// ---------------------------------------------------------------------------
// fp16 pull, 2-deep unroll: lane = g*8+q; per iteration TWO independent
// 8-row batches (16 rows) so the two load chains overlap (counted vmcnt).
// For deg<=8 rows batch 2 degenerates to value-selected row-0 loads (L1-hot).
// 32-bit element offsets -> saddr+voffset addressing.
__global__ __launch_bounds__(256) void pull_kernel(const _Float16* __restrict__ xhs,
                                                   const float* __restrict__ inv,
                                                   const int* __restrict__ rowptr,
                                                   const int* __restrict__ adj,
                                                   half8* __restrict__ out) {
    int t = blockIdx.x * 256 + threadIdx.x;
    int v = t >> 6;
    int lane = t & 63;
    int g = lane >> 3;        // neighbor slot (0..7)
    int q = lane & 7;         // feature octet (features 8q..8q+7)
    int beg = rowptr[v];
    int end = rowptr[v + 1];
    float acc[8] = {0.f, 0.f, 0.f, 0.f, 0.f, 0.f, 0.f, 0.f};
    for (int j = beg; j < end; j += 16) {
        int i0 = j + g;
        int i1 = i0 + 8;
        bool v0 = i0 < end;
        bool v1 = i1 < end;
        int n0 = v0 ? adj[i0] : 0;    // adj[i] for i<2E+16 stays inside ws (rk)
        int n1 = v1 ? adj[i1] : 0;
        float w0 = v0 ? inv[n0] : 0.0f;
        float w1 = v1 ? inv[n1] : 0.0f;
        half8 a0 = *(const half8*)(xhs + ((unsigned)n0 * 64u + (unsigned)q * 8u));
        half8 a1 = *(const half8*)(xhs + ((unsigned)n1 * 64u + (unsigned)q * 8u));
#pragma unroll
        for (int k = 0; k < 8; ++k) acc[k] += w0 * (float)a0[k];
#pragma unroll
        for (int k = 0; k < 8; ++k) acc[k] += w1 * (float)a1[k];
    }
    // combine the 8 neighbor slots (g occupies lane bits 3..5)
#pragma unroll
    for (int k = 0; k < 8; ++k) {
        acc[k] += __shfl_xor(acc[k], 8);
        acc[k] += __shfl_xor(acc[k], 16);
        acc[k] += __shfl_xor(acc[k], 32);
    }
    if (g == 0) {
        float iv = inv[v];
        half8 o;
#pragma unroll
        for (int k = 0; k < 8; ++k) o[k] = (_Float16)(iv * acc[k]);
        out[(size_t)v * 8 + q] = o;
    }
}

// ---------------------------------------------------------------------------
// Per-node tail: layer-3 pull + redistribute to lane-per-feature, returns
// Zfinal[lane] = Zrow[lane](emb+l1, f32) + x2[node][lane](fp16) + inv*pull.
__device__ __forceinline__ float node_final(int node,
                                            const float* __restrict__ Zrow,
                                            const _Float16* __restrict__ xhs,
                                            const float* __restrict__ inv,
                                            const int* __restrict__ rowptr,
                                            const int* __restrict__ adj,
                                            int lane, int g, int q) {
    int beg = rowptr[node];
    int end = rowptr[node + 1];
    float acc[8] = {0.f, 0.f, 0.f, 0.f, 0.f, 0.f, 0.f, 0.f};
    for (int j = beg; j < end; j += 16) {
        int i0 = j + g;
        int i1 = i0 + 8;
        bool v0 = i0 < end;
        bool v1 = i1 < end;
        int n0 = v0 ? adj[i0] : 0;
        int n1 = v1 ? adj[i1] : 0;
        float w0 = v0 ? inv[n0] : 0.0f;
        float w1 = v1 ? inv[n1] : 0.0f;
        half8 a0 = *(const half8*)(xhs + ((unsigned)n0 * 64u + (unsigned)q * 8u));
        half8 a1 = *(const half8*)(xhs + ((unsigned)n1 * 64u + (unsigned)q * 8u));
#pragma unroll
        for (int k = 0; k < 8; ++k) acc[k] += w0 * (float)a0[k];
#pragma unroll
        for (int k = 0; k < 8; ++k) acc[k] += w1 * (float)a1[k];
    }
#pragma unroll
    for (int k = 0; k < 8; ++k) {
        acc[k] += __shfl_xor(acc[k], 8);
        acc[k] += __shfl_xor(acc[k], 16);
        acc[k] += __shfl_xor(acc[k], 32);
    }
    // redistribute: lane wants feature `lane` = 8*(lane>>3) + (lane&7)
    float red = 0.0f;
#pragma unroll
    for (int k = 0; k < 8; ++k) {
        float tmp = __shfl(acc[k], lane >> 3);
        red = ((lane & 7) == k) ? tmp : red;
    }
    float x2 = (float)xhs[(unsigned)node * 64u + (unsigned)lane];
    return Zrow[lane] + x2 + inv[node] * red;
}

// ---------------------------------------------------------------------------
// Fused layer-2-acc + layer-3 pull + score: one wave per pair b.
// Zu/Zi hold emb(f32)+layer1. x2 (layer-2) is added here, layer-3 pulled
// in-register, and the factor-correlation score computed via shuffles.
__global__ __launch_bounds__(256) void pullz_score_kernel(
        const _Float16* __restrict__ xhs,     // layer-2 X
        const float* __restrict__ inv,
        const int* __restrict__ rowptr,
        const int* __restrict__ adj,
        const int* __restrict__ users,
        const int* __restrict__ items,
        const float* __restrict__ Zu,
        const float* __restrict__ Zi,
        const float* __restrict__ fw,
        float* __restrict__ out) {
    int t = blockIdx.x * 256 + threadIdx.x;
    int b = t >> 6;
    int lane = t & 63;
    int g = lane >> 3;
    int q = lane & 7;

    int u  = users[b];
    int it = items[b] + NU_;
    float zu = node_final(u,  Zu + (size_t)b * D_, xhs, inv, rowptr, adj, lane, g, q);
    float zi = node_final(it, Zi + (size_t)b * D_, xhs, inv, rowptr, adj, lane, g, q);

    // score: s = sum_{f,gg} fw[f,gg] * dot(zu[f*16: ], zi[gg*16: ])
    int f = lane >> 4;
    float s = 0.0f;
#pragma unroll
    for (int gg = 0; gg < 4; ++gg) {
        float pi = __shfl(zi, (gg << 4) | (lane & 15));
        float p = zu * pi;
        p += __shfl_xor(p, 1);
        p += __shfl_xor(p, 2);
        p += __shfl_xor(p, 4);
        p += __shfl_xor(p, 8);
        s += fw[f * 4 + gg] * p;
    }
    s += __shfl_xor(s, 16);
    s += __shfl_xor(s, 32);
    if (lane == 0) out[b] = s * 0.0625f;  // (1/4)*(1/4) layer-mean scaling
}

// ---------------------------------------------------------------------------
// Fused Z init + layer-1 accumulate: Z = emb(f32, exact) + layer1(fp16).
__global__ __launch_bounds__(256) void zinit_acc_kernel(const float* __restrict__ ue,
                                                        const float* __restrict__ ie,
                                                        const half4* __restrict__ xh,
                                                        const int* __restrict__ users,
                                                        const int* __restrict__ items,
                                                        float* __restrict__ Zu,
                                                        float* __restrict__ Zi) {
    int t = blockIdx.x * 256 + threadIdx.x;
    int b = t >> 4;
    int q = t & 15;
    size_t node;
    const float4* ep;
    float4* zp;
    if (b < B_) {
        node = (size_t)users[b];
        ep = (const float4*)(ue + node * D_) + q;
        zp = (float4*)(Zu + (size_t)b * D_) + q;
    } else {
        int bb = b - B_;
        node = (size_t)items[bb] + NU_;
        ep = (const float4*)(ie + (size_t)items[bb] * D_) + q;
        zp = (float4*)(Zi + (size_t)bb * D_) + q;
    }
    half4 a = xh[node * 16 + q];
    float4 z = *ep;
    z.x += (float)a[0]; z.y += (float)a[1];
    z.z += (float)a[2]; z.w += (float)a[3];
    *zp = z;
}

// ---------------------------------------------------------------------------
extern "C" void kernel_launch(void* const* d_in, const int* in_sizes, int n_in,
                              void* d_out, int out_size, void* d_ws, size_t ws_size,
                              hipStream_t stream) {
    const float* ue    = (const float*)d_in[0];  // [NU, 64]
    const float* ie    = (const float*)d_in[1];  // [NI, 64]
    const float* fw    = (const float*)d_in[2];  // [4, 4]
    const int*   eu    = (const int*)d_in[3];    // [E]
    const int*   eitem = (const int*)d_in[4];    // [E]
    const int*   users = (const int*)d_in[5];    // [B]
    const int*   items = (const int*)d_in[6];    // [B]
    float* scores = (float*)d_out;               // [B]

    const size_t xh_bytes = (size_t)NN_ * D_ * 2;             // 89.6 MB (fp16)
    const size_t zbytes   = (size_t)B_ * D_ * sizeof(float);  // 33.55 MB
    const int NB_SCAN = (NN_ + 1023) / 1024;                  // 684

    char* ws = (char*)d_ws;
    half8* X0h   = (half8*)ws;  ws += xh_bytes;   // layer-0; reused as layer-2 out
    half8* XAh   = (half8*)ws;  ws += xh_bytes;   // layer-1
    float* Zu    = (float*)ws;  ws += zbytes;
    float* Zi    = (float*)ws;  ws += zbytes;
    float* inv   = (float*)ws;  ws += (size_t)NN_ * 4;
    int*   cnt   = (int*)ws;    ws += (size_t)NN_ * 4;
    int*   rowptr= (int*)ws;    ws += (size_t)(NN_ + 1) * 4;
    int*   adj   = (int*)ws;    ws += (size_t)TWO_E * 4;      // 16 MB compact
    int*   rk    = (int*)ws;    ws += (size_t)TWO_E * 4;      // 16 MB ranks
    int*   psum  = (int*)ws;    ws += (size_t)NB_SCAN * 4;
    int*   poff  = (int*)ws;    ws += (size_t)NB_SCAN * 4;
    half8* XBh   = X0h;         // ping-pong: X0h dead after layer-1 pull

    // --- CSR build: rank-from-degree + atomicExch fill -----------------
    hipMemsetAsync(cnt, 0, (size_t)NN_ * 4, stream);
    deg_rank_kernel<<<TWO_E / 256, 256, 0, stream>>>(eu, eitem, cnt, rk);
    inv_kernel<<<(NN_ + 255) / 256, 256, 0, stream>>>(cnt, inv);
    scan_block<<<NB_SCAN, 1024, 0, stream>>>(cnt, NN_, rowptr, psum);
    scan_block<<<1, 1024, 0, stream>>>(psum, NB_SCAN, poff, (int*)nullptr);
    scan_add<<<(NN_ + 255) / 256, 256, 0, stream>>>(rowptr, poff);
    fill2_kernel<<<TWO_E / 256, 256, 0, stream>>>(eu, eitem, rk, rowptr, adj);

    // --- fp16 conversion of layer-0 X ----------------------------------
    conv_kernel<<<(NN_ * 16) / 256, 256, 0, stream>>>(ue, ie, (half4*)X0h);

    // --- propagation ----------------------------------------------------
    pull_kernel<<<(NN_ * D_) / 256, 256, 0, stream>>>(
        (const _Float16*)X0h, inv, rowptr, adj, XAh);
    // Z = emb(f32) + layer1, fused
    zinit_acc_kernel<<<(2 * B_ * 16) / 256, 256, 0, stream>>>(
        ue, ie, (const half4*)XAh, users, items, Zu, Zi);
    pull_kernel<<<(NN_ * D_) / 256, 256, 0, stream>>>(
        (const _Float16*)XAh, inv, rowptr, adj, XBh);
    // layer-2 acc + layer-3 pull + score, all fused per pair
    pullz_score_kernel<<<(B_ * D_) / 256, 256, 0, stream>>>(
        (const _Float16*)XBh, inv, rowptr, adj, users, items, Zu, Zi, fw, scores);
}